// Round 12
// baseline (245.664 us; speedup 1.0000x reference)
//
#include <hip/hip_runtime.h>
#include <hip/hip_bf16.h>

#define NTOK 2048
#define NHEADS 12
#define HDIM 64
#define DIM 768
#define BATCH 4
// exp2-domain: p = exp(QK*0.125 + bias - 16) = exp2(QK*SC2 + bias*LOG2E - SHIFT2)
#define SC2_    0.18033688011112042f
#define LOG2E_  1.4426950408889634f
#define SHIFT2_ 23.083120654223415f

typedef __attribute__((ext_vector_type(8))) short short8;
typedef __attribute__((ext_vector_type(4))) float f32x4;
typedef __attribute__((ext_vector_type(16))) float f32x16;

__device__ __forceinline__ short f2bf(float f) {
  union { float f; unsigned u; } v; v.f = f;
  unsigned r = v.u + 0x7fffu + ((v.u >> 16) & 1u);
  return (short)(r >> 16);
}

__device__ __forceinline__ f32x4 mfma_bf16(short8 a, short8 b, f32x4 c) {
  return __builtin_amdgcn_mfma_f32_16x16x32_bf16(a, b, c, 0, 0, 0);
}

__device__ __forceinline__ f32x16 mfma32(short8 a, short8 b, f32x16 c) {
  return __builtin_amdgcn_mfma_f32_32x32x16_bf16(a, b, c, 0, 0, 0);
}

__device__ __forceinline__ void gload_lds16(const void* g, void* l) {
  __builtin_amdgcn_global_load_lds((const __attribute__((address_space(1))) void*)g,
                                   (__attribute__((address_space(3))) void*)l, 16, 0, 0);
}

__device__ __forceinline__ float exp2_hw(float x) {
  float r; asm("v_exp_f32 %0, %1" : "=v"(r) : "v"(x)); return r;
}

__device__ __forceinline__ unsigned cvt_pk_bf16(float lo, float hi) {
  unsigned r; asm("v_cvt_pk_bf16_f32 %0, %1, %2" : "=v"(r) : "v"(lo), "v"(hi)); return r;
}

__device__ __forceinline__ int swz(int r) { return (r ^ (r >> 3)) & 7; }

// ---------------- fp32 -> bf16 conversion ----------------
__global__ void cvt_x(const float* __restrict__ src, short* __restrict__ dst) {
  int i = blockIdx.x * 256 + threadIdx.x;
  float4 v = ((const float4*)src)[i];
  short4 o; o.x = f2bf(v.x); o.y = f2bf(v.y); o.z = f2bf(v.z); o.w = f2bf(v.w);
  ((short4*)dst)[i] = o;
}

__global__ void cvt_w(const float* __restrict__ w0, const float* __restrict__ w1,
                      const float* __restrict__ w2, const float* __restrict__ w3,
                      short* __restrict__ d0, short* __restrict__ d1,
                      short* __restrict__ d2, short* __restrict__ d3) {
  int i = blockIdx.x * 256 + threadIdx.x;
  const float* s = blockIdx.y == 0 ? w0 : blockIdx.y == 1 ? w1 : blockIdx.y == 2 ? w2 : w3;
  short* d = blockIdx.y == 0 ? d0 : blockIdx.y == 1 ? d1 : blockIdx.y == 2 ? d2 : d3;
  float4 v = ((const float4*)s)[i];
  short4 o; o.x = f2bf(v.x); o.y = f2bf(v.y); o.z = f2bf(v.z); o.w = f2bf(v.w);
  ((short4*)d)[i] = o;
}

// ---------------- shared GEMM main loop: 128x128 tile, BK=64 ----------------
__device__ __forceinline__ void gemm_mainloop(const short* __restrict__ A,
                                              const short* __restrict__ B,
                                              int mbase, int nbase,
                                              short* As, short* Bs,
                                              f32x4 (&acc)[4][4], int lane, int w) {
  int lr = lane & 15, lg = lane >> 4;
  int wr = w >> 1, wc = w & 1;
  for (int kb = 0; kb < DIM; kb += 64) {
    if (kb) __syncthreads();
#pragma unroll
    for (int c = 0; c < 4; ++c) {
      int row = w * 32 + c * 8 + (lane >> 3);
      int sch = (lane & 7) ^ (row & 7);
      gload_lds16(A + (size_t)(mbase + row) * DIM + kb + sch * 8, (char*)As + w * 4096 + c * 1024);
      gload_lds16(B + (size_t)(nbase + row) * DIM + kb + sch * 8, (char*)Bs + w * 4096 + c * 1024);
    }
    __syncthreads();
#pragma unroll
    for (int ks = 0; ks < 2; ++ks) {
      short8 af[4], bf[4];
#pragma unroll
      for (int i = 0; i < 4; ++i) {
        int row = wr * 64 + i * 16 + lr;
        int ch = (ks * 4 + lg) ^ (row & 7);
        af[i] = *(const short8*)(As + row * 64 + ch * 8);
      }
#pragma unroll
      for (int j = 0; j < 4; ++j) {
        int row = wc * 64 + j * 16 + lr;
        int ch = (ks * 4 + lg) ^ (row & 7);
        bf[j] = *(const short8*)(Bs + row * 64 + ch * 8);
      }
#pragma unroll
      for (int i = 0; i < 4; ++i)
#pragma unroll
        for (int j = 0; j < 4; ++j)
          acc[i][j] = mfma_bf16(af[i], bf[j], acc[i][j]);
    }
  }
}

// ---------------- QKV projection ----------------
__global__ __launch_bounds__(256, 2) void gemm_qkv(const short* __restrict__ xb,
    const short* __restrict__ wq, const short* __restrict__ wk, const short* __restrict__ wv,
    short* __restrict__ Qh, short* __restrict__ Kh, short* __restrict__ Vt) {
  __shared__ __align__(16) short As[128 * 64];
  __shared__ __align__(16) short Bs[128 * 64];
  int nt = blockIdx.x, mt = blockIdx.y, z = blockIdx.z;
  const short* B = z == 0 ? wq : (z == 1 ? wk : wv);
  int tid = threadIdx.x, lane = tid & 63, w = tid >> 6;
  f32x4 acc[4][4] = {};
  gemm_mainloop(xb, B, mt * 128, nt * 128, As, Bs, acc, lane, w);
  int lr = lane & 15, lg = lane >> 4, wr = w >> 1, wc = w & 1;
  if (z < 2) {
    short* dst = z == 0 ? Qh : Kh;
#pragma unroll
    for (int i = 0; i < 4; ++i)
#pragma unroll
      for (int j = 0; j < 4; ++j) {
        int m = mt * 128 + wr * 64 + i * 16 + lg * 4;
        int n = nt * 128 + wc * 64 + j * 16 + lr;
        int bb = m >> 11, nn = m & 2047, hh = n >> 6, d = n & 63;
        size_t base = (((size_t)bb * NHEADS + hh) * NTOK + nn) * HDIM + d;
#pragma unroll
        for (int r = 0; r < 4; ++r)
          dst[base + (size_t)r * HDIM] = f2bf(acc[i][j][r]);
      }
  } else {
#pragma unroll
    for (int i = 0; i < 4; ++i)
#pragma unroll
      for (int j = 0; j < 4; ++j) {
        int m = mt * 128 + wr * 64 + i * 16 + lg * 4;
        int n = nt * 128 + wc * 64 + j * 16 + lr;
        int bb = m >> 11, nn = m & 2047, hh = n >> 6, d = n & 63;
        short4 pk;
        pk.x = f2bf(acc[i][j][0]); pk.y = f2bf(acc[i][j][1]);
        pk.z = f2bf(acc[i][j][2]); pk.w = f2bf(acc[i][j][3]);
        *(short4*)(Vt + (((size_t)bb * NHEADS + hh) * HDIM + d) * NTOK + nn) = pk;
      }
  }
}

// ---------------- fused flash attention ----------------
// 768 blocks (XCD-remapped). 4 waves/block, wave owns 32 q rows via 32x32x16
// MFMA (both matmuls operand-swapped, P in registers via cvt_pk+permlane).
// KVBLK=32; K, V, BIAS staged via contiguous global_load_lds. TRIPLE buffer,
// depth-2 prefetch: stage(t+2) issued at tile t top; tile end does counted
// s_waitcnt vmcnt(6) (stage t+1 done, t+2 still in flight) + raw s_barrier +
// sched_barrier(0) -- vmcnt never drains to 0 in the loop, so L3 bias
// latency (~800cy) is covered by ~2 tiles of compute (the r11 residual
// stall was __syncthreads' vmcnt(0) drain). LDS 72KB -> 2 blocks/CU.
__global__ __launch_bounds__(256, 2) void attn_fused(const short* __restrict__ Qh,
    const short* __restrict__ Kh, const short* __restrict__ Vt,
    const float* __restrict__ bias, short* __restrict__ Ob) {
  __shared__ __align__(16) short Ks[3][32 * 64];   // [kvrow][d]      12 KB
  __shared__ __align__(16) short Vs[3][32 * 64];   // packed V^T      12 KB
  __shared__ __align__(16) float Bs[3][128 * 32];  // [qrow][kvcol]   48 KB
  int d0 = blockIdx.x;
  int wg = (d0 & 7) * 96 + (d0 >> 3);          // bijective: 768 = 8*96
  int b = wg & 3, qb = (wg >> 2) & 15, h = wg >> 6;
  int tid = threadIdx.x, lane = tid & 63, w = tid >> 6;
  int ql = lane & 31, hi = lane >> 5;

  const short* Q = Qh + ((size_t)b * NHEADS + h) * NTOK * HDIM;
  const short* K = Kh + ((size_t)b * NHEADS + h) * NTOK * HDIM;
  const short* V = Vt + ((size_t)b * NHEADS + h) * HDIM * NTOK;
  int qrow = qb * 128 + w * 32 + ql;
  const float* Bg = bias + ((size_t)h * NTOK + qb * 128) * NTOK;  // block rows

  short8 qf[4];
#pragma unroll
  for (int i = 0; i < 4; ++i)
    qf[i] = *(const short8*)(Q + (size_t)qrow * HDIM + i * 16 + hi * 8);

  float psum = 0.f;
  f32x16 oacc0 = {}, oacc1 = {};

  int l8 = lane >> 3, s7 = lane & 7;

#define STAGE_ALL(BUF, KV)                                                     \
  {                                                                            \
    int krow = w * 8 + l8;                                                     \
    gload_lds16(K + (size_t)((KV) + krow) * HDIM + ((s7 ^ swz(krow)) * 8),     \
                (char*)Ks[BUF] + w * 1024);                                    \
    int vrp = w * 8 + l8;                                                      \
    int vu = s7 ^ swz(vrp);                                                    \
    gload_lds16(V + (size_t)(vrp * 2 + (vu >> 2)) * NTOK + (KV) + (vu & 3) * 8,\
                (char*)Vs[BUF] + w * 1024);                                    \
    _Pragma("unroll")                                                          \
    for (int j = 0; j < 4; ++j) {                                              \
      int brow = w * 32 + j * 8 + l8;                                          \
      gload_lds16(Bg + (size_t)brow * NTOK + (KV) + ((s7 ^ swz(brow)) * 4),    \
                  (char*)Bs[BUF] + w * 4096 + j * 1024);                       \
    }                                                                          \
  }

  STAGE_ALL(0, 0)
  STAGE_ALL(1, 32)
  asm volatile("s_waitcnt vmcnt(6)" ::: "memory");   // stage(0) landed
  __builtin_amdgcn_s_barrier();
  __builtin_amdgcn_sched_barrier(0);

  for (int t = 0; t < NTOK / 32; ++t) {
    int cur = t % 3;
    int kv = t * 32;
    if (t < NTOK / 32 - 2) STAGE_ALL((t + 2) % 3, kv + 64)

    const short* Kc = Ks[cur];
    const short* Vc = Vs[cur];
    const float* Bc = Bs[cur];

    // S^T = K Q^T : lane holds k = (reg&3)+8*(reg>>2)+4*hi, q = ql
    f32x16 sacc = {};
    __builtin_amdgcn_s_setprio(1);
#pragma unroll
    for (int i = 0; i < 4; ++i) {
      short8 kf = *(const short8*)(Kc + ql * 64 + (((i * 2 + hi) ^ swz(ql)) * 8));
      sacc = mfma32(kf, qf[i], sacc);
    }
    __builtin_amdgcn_s_setprio(0);

    // bias from LDS: bvr[g] = bias[qrow][8g + 4hi + 0..3]
    f32x4 bvr[4];
    int brow = w * 32 + ql;
#pragma unroll
    for (int g = 0; g < 4; ++g)
      bvr[g] = *(const f32x4*)(Bc + brow * 32 + (((g * 2 + hi) ^ swz(brow)) * 4));

    // p = exp2(S*SC2 + bias*LOG2E - SHIFT2)
    float p[16];
#pragma unroll
    for (int rg = 0; rg < 16; ++rg) {
      float tb = fmaf(bvr[rg >> 2][rg & 3], LOG2E_, -SHIFT2_);
      p[rg] = exp2_hw(fmaf(sacc[rg], SC2_, tb));
    }
    float ts = 0.f;
#pragma unroll
    for (int g = 0; g < 4; ++g)
      ts += (p[g * 4] + p[g * 4 + 1]) + (p[g * 4 + 2] + p[g * 4 + 3]);
    psum += ts;

    unsigned Wd[4][2];
#pragma unroll
    for (int g = 0; g < 4; ++g) {
      Wd[g][0] = cvt_pk_bf16(p[g * 4], p[g * 4 + 1]);
      Wd[g][1] = cvt_pk_bf16(p[g * 4 + 2], p[g * 4 + 3]);
    }

    // PV: rebuild B-frag via permlane32_swap; A = packed V^T rows from LDS
#pragma unroll
    for (int cc = 0; cc < 2; ++cc) {
      auto r0 = __builtin_amdgcn_permlane32_swap(Wd[cc * 2][0], Wd[cc * 2 + 1][0], false, false);
      auto r1 = __builtin_amdgcn_permlane32_swap(Wd[cc * 2][1], Wd[cc * 2 + 1][1], false, false);
      union { unsigned u[4]; short8 s; } pb;
      pb.u[0] = r0[0]; pb.u[1] = r1[0]; pb.u[2] = r0[1]; pb.u[3] = r1[1];
      __builtin_amdgcn_s_setprio(1);
      {
        int rp0 = (ql >> 1);
        int s0 = (((ql & 1) * 4 + cc * 2 + hi) ^ swz(rp0));
        short8 vf0 = *(const short8*)(Vc + rp0 * 64 + s0 * 8);
        oacc0 = mfma32(vf0, pb.s, oacc0);
        int rp1 = 16 + (ql >> 1);
        int s1 = (((ql & 1) * 4 + cc * 2 + hi) ^ swz(rp1));
        short8 vf1 = *(const short8*)(Vc + rp1 * 64 + s1 * 8);
        oacc1 = mfma32(vf1, pb.s, oacc1);
      }
      __builtin_amdgcn_s_setprio(0);
    }

    if (t < NTOK / 32 - 1) {
      if (t < NTOK / 32 - 2)
        asm volatile("s_waitcnt vmcnt(6)" ::: "memory");  // stage(t+1) landed
      else
        asm volatile("s_waitcnt vmcnt(0)" ::: "memory");  // last stage landed
      __builtin_amdgcn_s_barrier();
      __builtin_amdgcn_sched_barrier(0);
    }
  }
#undef STAGE_ALL

  // epilogue: row-sum finish (one xor-32), normalize, pack, store
  float fs = psum + __shfl_xor(psum, 32);
  float inv = 1.f / fs;
  size_t obase = ((size_t)b * NTOK + qrow) * DIM + h * HDIM;
#pragma unroll
  for (int g = 0; g < 4; ++g) {
    unsigned u0 = cvt_pk_bf16(oacc0[g * 4] * inv, oacc0[g * 4 + 1] * inv);
    unsigned u1 = cvt_pk_bf16(oacc0[g * 4 + 2] * inv, oacc0[g * 4 + 3] * inv);
    uint2 pk0; pk0.x = u0; pk0.y = u1;
    *(uint2*)(Ob + obase + g * 8 + hi * 4) = pk0;
    unsigned u2 = cvt_pk_bf16(oacc1[g * 4] * inv, oacc1[g * 4 + 1] * inv);
    unsigned u3 = cvt_pk_bf16(oacc1[g * 4 + 2] * inv, oacc1[g * 4 + 3] * inv);
    uint2 pk1; pk1.x = u2; pk1.y = u3;
    *(uint2*)(Ob + obase + 32 + g * 8 + hi * 4) = pk1;
  }
}

// ---------------- output projection ----------------
__global__ __launch_bounds__(256, 2) void gemm_proj(const short* __restrict__ Ob,
    const short* __restrict__ wp, const float* __restrict__ bp, float* __restrict__ out) {
  __shared__ __align__(16) short As[128 * 64];
  __shared__ __align__(16) short Bs[128 * 64];
  int nt = blockIdx.x, mt = blockIdx.y;
  int tid = threadIdx.x, lane = tid & 63, w = tid >> 6;
  f32x4 acc[4][4] = {};
  gemm_mainloop(Ob, wp, mt * 128, nt * 128, As, Bs, acc, lane, w);
  int lr = lane & 15, lg = lane >> 4, wr = w >> 1, wc = w & 1;
#pragma unroll
  for (int j = 0; j < 4; ++j) {
    int n = nt * 128 + wc * 64 + j * 16 + lr;
    float bpv = bp[n];
#pragma unroll
    for (int i = 0; i < 4; ++i) {
      int m = mt * 128 + wr * 64 + i * 16 + lg * 4;
#pragma unroll
      for (int r = 0; r < 4; ++r)
        out[(size_t)(m + r) * DIM + n] = acc[i][j][r] + bpv;
    }
  }
}

extern "C" void kernel_launch(void* const* d_in, const int* in_sizes, int n_in,
                              void* d_out, int out_size, void* d_ws, size_t ws_size,
                              hipStream_t stream) {
  const float* x    = (const float*)d_in[0];
  const float* bias = (const float*)d_in[1];
  const float* Wq   = (const float*)d_in[2];
  const float* Wk   = (const float*)d_in[3];
  const float* Wv   = (const float*)d_in[4];
  const float* Wp   = (const float*)d_in[5];
  const float* bp   = (const float*)d_in[6];
  float* out = (float*)d_out;

  char* ws = (char*)d_ws;
  short* xb  = (short*)(ws);                    // 8192*768 bf16
  short* wqb = (short*)(ws + 12582912);
  short* wkb = (short*)(ws + 13762560);
  short* wvb = (short*)(ws + 14942208);
  short* wpb = (short*)(ws + 16121856);
  short* Qh  = (short*)(ws + 17301504);         // [b][h][n][64]
  short* Kh  = (short*)(ws + 29884416);
  short* Vt  = (short*)(ws + 42467328);         // [b][h][64][n]
  short* Ob  = (short*)(ws + 55050240);         // [b][n][768]

  cvt_x<<<6144, 256, 0, stream>>>(x, xb);
  cvt_w<<<dim3(576, 4), 256, 0, stream>>>(Wq, Wk, Wv, Wp, wqb, wkb, wvb, wpb);
  gemm_qkv<<<dim3(6, 64, 3), 256, 0, stream>>>(xb, wqb, wkb, wvb, Qh, Kh, Vt);
  attn_fused<<<768, 256, 0, stream>>>(Qh, Kh, Vt, bias, Ob);
  gemm_proj<<<dim3(6, 64), 256, 0, stream>>>(Ob, wpb, bp, out);
}

// Round 13
// 195.620 us; speedup vs baseline: 1.2558x; 1.2558x over previous
//
#include <hip/hip_runtime.h>
#include <hip/hip_bf16.h>

#define NTOK 2048
#define NHEADS 12
#define HDIM 64
#define DIM 768
#define BATCH 4
// Q is pre-scaled by SC2 = 0.125*log2(e) in gemm_qkv, so
// p = exp2( fmaf(bias, LOG2E, qk_scaled) ); normalization cancels any shift.
#define SC2_    0.18033688011112042f
#define LOG2E_  1.4426950408889634f

typedef __attribute__((ext_vector_type(8))) short short8;
typedef __attribute__((ext_vector_type(4))) float f32x4;
typedef __attribute__((ext_vector_type(16))) float f32x16;

__device__ __forceinline__ short f2bf(float f) {
  union { float f; unsigned u; } v; v.f = f;
  unsigned r = v.u + 0x7fffu + ((v.u >> 16) & 1u);
  return (short)(r >> 16);
}

__device__ __forceinline__ f32x4 mfma_bf16(short8 a, short8 b, f32x4 c) {
  return __builtin_amdgcn_mfma_f32_16x16x32_bf16(a, b, c, 0, 0, 0);
}

__device__ __forceinline__ f32x16 mfma32(short8 a, short8 b, f32x16 c) {
  return __builtin_amdgcn_mfma_f32_32x32x16_bf16(a, b, c, 0, 0, 0);
}

__device__ __forceinline__ void gload_lds16(const void* g, void* l) {
  __builtin_amdgcn_global_load_lds((const __attribute__((address_space(1))) void*)g,
                                   (__attribute__((address_space(3))) void*)l, 16, 0, 0);
}

__device__ __forceinline__ float exp2_hw(float x) {
  float r; asm("v_exp_f32 %0, %1" : "=v"(r) : "v"(x)); return r;
}

__device__ __forceinline__ unsigned cvt_pk_bf16(float lo, float hi) {
  unsigned r; asm("v_cvt_pk_bf16_f32 %0, %1, %2" : "=v"(r) : "v"(lo), "v"(hi)); return r;
}

__device__ __forceinline__ int swz(int r) { return (r ^ (r >> 3)) & 7; }

// ---------------- fp32 -> bf16 conversion ----------------
__global__ void cvt_x(const float* __restrict__ src, short* __restrict__ dst) {
  int i = blockIdx.x * 256 + threadIdx.x;
  float4 v = ((const float4*)src)[i];
  short4 o; o.x = f2bf(v.x); o.y = f2bf(v.y); o.z = f2bf(v.z); o.w = f2bf(v.w);
  ((short4*)dst)[i] = o;
}

__global__ void cvt_w(const float* __restrict__ w0, const float* __restrict__ w1,
                      const float* __restrict__ w2, const float* __restrict__ w3,
                      short* __restrict__ d0, short* __restrict__ d1,
                      short* __restrict__ d2, short* __restrict__ d3) {
  int i = blockIdx.x * 256 + threadIdx.x;
  const float* s = blockIdx.y == 0 ? w0 : blockIdx.y == 1 ? w1 : blockIdx.y == 2 ? w2 : w3;
  short* d = blockIdx.y == 0 ? d0 : blockIdx.y == 1 ? d1 : blockIdx.y == 2 ? d2 : d3;
  float4 v = ((const float4*)s)[i];
  short4 o; o.x = f2bf(v.x); o.y = f2bf(v.y); o.z = f2bf(v.z); o.w = f2bf(v.w);
  ((short4*)d)[i] = o;
}

// ---------------- shared GEMM main loop: 128x128 tile, BK=64 ----------------
__device__ __forceinline__ void gemm_mainloop(const short* __restrict__ A,
                                              const short* __restrict__ B,
                                              int mbase, int nbase,
                                              short* As, short* Bs,
                                              f32x4 (&acc)[4][4], int lane, int w) {
  int lr = lane & 15, lg = lane >> 4;
  int wr = w >> 1, wc = w & 1;
  for (int kb = 0; kb < DIM; kb += 64) {
    if (kb) __syncthreads();
#pragma unroll
    for (int c = 0; c < 4; ++c) {
      int row = w * 32 + c * 8 + (lane >> 3);
      int sch = (lane & 7) ^ (row & 7);
      gload_lds16(A + (size_t)(mbase + row) * DIM + kb + sch * 8, (char*)As + w * 4096 + c * 1024);
      gload_lds16(B + (size_t)(nbase + row) * DIM + kb + sch * 8, (char*)Bs + w * 4096 + c * 1024);
    }
    __syncthreads();
#pragma unroll
    for (int ks = 0; ks < 2; ++ks) {
      short8 af[4], bf[4];
#pragma unroll
      for (int i = 0; i < 4; ++i) {
        int row = wr * 64 + i * 16 + lr;
        int ch = (ks * 4 + lg) ^ (row & 7);
        af[i] = *(const short8*)(As + row * 64 + ch * 8);
      }
#pragma unroll
      for (int j = 0; j < 4; ++j) {
        int row = wc * 64 + j * 16 + lr;
        int ch = (ks * 4 + lg) ^ (row & 7);
        bf[j] = *(const short8*)(Bs + row * 64 + ch * 8);
      }
#pragma unroll
      for (int i = 0; i < 4; ++i)
#pragma unroll
        for (int j = 0; j < 4; ++j)
          acc[i][j] = mfma_bf16(af[i], bf[j], acc[i][j]);
    }
  }
}

// ---------------- QKV projection ----------------
__global__ __launch_bounds__(256, 2) void gemm_qkv(const short* __restrict__ xb,
    const short* __restrict__ wq, const short* __restrict__ wk, const short* __restrict__ wv,
    short* __restrict__ Qh, short* __restrict__ Kh, short* __restrict__ Vt) {
  __shared__ __align__(16) short As[128 * 64];
  __shared__ __align__(16) short Bs[128 * 64];
  int nt = blockIdx.x, mt = blockIdx.y, z = blockIdx.z;
  const short* B = z == 0 ? wq : (z == 1 ? wk : wv);
  int tid = threadIdx.x, lane = tid & 63, w = tid >> 6;
  f32x4 acc[4][4] = {};
  gemm_mainloop(xb, B, mt * 128, nt * 128, As, Bs, acc, lane, w);
  int lr = lane & 15, lg = lane >> 4, wr = w >> 1, wc = w & 1;
  if (z < 2) {
    short* dst = z == 0 ? Qh : Kh;
    float sc = z == 0 ? SC2_ : 1.f;   // pre-scale Q by SC2 (free here)
#pragma unroll
    for (int i = 0; i < 4; ++i)
#pragma unroll
      for (int j = 0; j < 4; ++j) {
        int m = mt * 128 + wr * 64 + i * 16 + lg * 4;
        int n = nt * 128 + wc * 64 + j * 16 + lr;
        int bb = m >> 11, nn = m & 2047, hh = n >> 6, d = n & 63;
        size_t base = (((size_t)bb * NHEADS + hh) * NTOK + nn) * HDIM + d;
#pragma unroll
        for (int r = 0; r < 4; ++r)
          dst[base + (size_t)r * HDIM] = f2bf(acc[i][j][r] * sc);
      }
  } else {
#pragma unroll
    for (int i = 0; i < 4; ++i)
#pragma unroll
      for (int j = 0; j < 4; ++j) {
        int m = mt * 128 + wr * 64 + i * 16 + lg * 4;
        int n = nt * 128 + wc * 64 + j * 16 + lr;
        int bb = m >> 11, nn = m & 2047, hh = n >> 6, d = n & 63;
        short4 pk;
        pk.x = f2bf(acc[i][j][0]); pk.y = f2bf(acc[i][j][1]);
        pk.z = f2bf(acc[i][j][2]); pk.w = f2bf(acc[i][j][3]);
        *(short4*)(Vt + (((size_t)bb * NHEADS + hh) * HDIM + d) * NTOK + nn) = pk;
      }
  }
}

// ---------------- fused flash attention ----------------
// r11 structure (48KB LDS, 3 blocks/CU, double-buffered K/V/bias staged via
// contiguous global_load_lds) with a minimized per-tile instruction stream:
// no shift (normalization cancels), Q pre-scaled by SC2 (exp arg = one fma),
// row-sum via ones-MFMA (colsum on the idle MFMA pipe), and all LDS/stage
// addresses hoisted out of the loop (2-unrolled bodies, literal buffer idx).
__global__ __launch_bounds__(256, 3) void attn_fused(const short* __restrict__ Qh,
    const short* __restrict__ Kh, const short* __restrict__ Vt,
    const float* __restrict__ bias, short* __restrict__ Ob) {
  __shared__ __align__(16) short Ks[2][32 * 64];   // 4 KB / buffer
  __shared__ __align__(16) short Vs[2][32 * 64];   // 4 KB / buffer
  __shared__ __align__(16) float Bsh[2][128 * 32]; // 16 KB / buffer
  int d0 = blockIdx.x;
  int wg = (d0 & 7) * 96 + (d0 >> 3);          // bijective: 768 = 8*96
  int b = wg & 3, qb = (wg >> 2) & 15, h = wg >> 6;
  int tid = threadIdx.x, lane = tid & 63, w = tid >> 6;
  int ql = lane & 31, hi = lane >> 5;

  const short* Q = Qh + ((size_t)b * NHEADS + h) * NTOK * HDIM;
  const short* K = Kh + ((size_t)b * NHEADS + h) * NTOK * HDIM;
  const short* V = Vt + ((size_t)b * NHEADS + h) * HDIM * NTOK;
  int qrow = qb * 128 + w * 32 + ql;
  const float* Bg = bias + ((size_t)h * NTOK + qb * 128) * NTOK;

  short8 qf[4];
#pragma unroll
  for (int i = 0; i < 4; ++i)
    qf[i] = *(const short8*)(Q + (size_t)qrow * HDIM + i * 16 + hi * 8);

  short8 onesv;
#pragma unroll
  for (int i = 0; i < 8; ++i) onesv[i] = (short)0x3F80;   // bf16 1.0

  f32x16 oacc0 = {}, oacc1 = {}, sumacc = {};

  int l8 = lane >> 3, s7 = lane & 7;

  // ---- stage source pointers (advance by constants per tile) ----
  int krow = w * 8 + l8;
  const short* Ksrc = K + (size_t)krow * HDIM + (s7 ^ swz(krow)) * 8;
  int vrp = w * 8 + l8;
  int vu = s7 ^ swz(vrp);
  const short* Vsrc = V + (size_t)(vrp * 2 + (vu >> 2)) * NTOK + (vu & 3) * 8;
  int br0 = w * 32 + 0 + l8, br1 = w * 32 + 8 + l8, br2 = w * 32 + 16 + l8, br3 = w * 32 + 24 + l8;
  const float* Bsrc0 = Bg + (size_t)br0 * NTOK + (s7 ^ swz(br0)) * 4;
  const float* Bsrc1 = Bg + (size_t)br1 * NTOK + (s7 ^ swz(br1)) * 4;
  const float* Bsrc2 = Bg + (size_t)br2 * NTOK + (s7 ^ swz(br2)) * 4;
  const float* Bsrc3 = Bg + (size_t)br3 * NTOK + (s7 ^ swz(br3)) * 4;
  char* Kdst = (char*)Ks[0] + w * 1024;
  char* Vdst = (char*)Vs[0] + w * 1024;
  char* Bdst = (char*)Bsh[0] + w * 4096;

  // ---- LDS read addresses (buffer 0; buffer 1 = +const folded to ds offset)
  int sq = swz(ql);
  const short* ka0 = Ks[0] + ql * 64 + ((0 + hi) ^ sq) * 8;
  const short* ka1 = Ks[0] + ql * 64 + ((2 + hi) ^ sq) * 8;
  const short* ka2 = Ks[0] + ql * 64 + ((4 + hi) ^ sq) * 8;
  const short* ka3 = Ks[0] + ql * 64 + ((6 + hi) ^ sq) * 8;
  int brow = w * 32 + ql, sb = swz(brow);
  const float* ba0 = Bsh[0] + brow * 32 + ((0 + hi) ^ sb) * 4;
  const float* ba1 = Bsh[0] + brow * 32 + ((2 + hi) ^ sb) * 4;
  const float* ba2 = Bsh[0] + brow * 32 + ((4 + hi) ^ sb) * 4;
  const float* ba3 = Bsh[0] + brow * 32 + ((6 + hi) ^ sb) * 4;
  int rp0 = ql >> 1, rp1 = 16 + (ql >> 1);
  int sv0 = swz(rp0), sv1 = swz(rp1);
  int q4 = (ql & 1) * 4 + hi;
  const short* va00 = Vs[0] + rp0 * 64 + ((q4 + 0) ^ sv0) * 8;
  const short* va01 = Vs[0] + rp1 * 64 + ((q4 + 0) ^ sv1) * 8;
  const short* va10 = Vs[0] + rp0 * 64 + ((q4 + 2) ^ sv0) * 8;
  const short* va11 = Vs[0] + rp1 * 64 + ((q4 + 2) ^ sv1) * 8;

#define STAGE(CUR)                                                            \
  {                                                                           \
    gload_lds16(Ksrc, Kdst + (CUR) * 4096);  Ksrc += 32 * HDIM;               \
    gload_lds16(Vsrc, Vdst + (CUR) * 4096);  Vsrc += 32;                      \
    gload_lds16(Bsrc0, Bdst + (CUR) * 16384);           Bsrc0 += 32;          \
    gload_lds16(Bsrc1, Bdst + (CUR) * 16384 + 1024);    Bsrc1 += 32;          \
    gload_lds16(Bsrc2, Bdst + (CUR) * 16384 + 2048);    Bsrc2 += 32;          \
    gload_lds16(Bsrc3, Bdst + (CUR) * 16384 + 3072);    Bsrc3 += 32;          \
  }

#define BODY(T, CUR)                                                          \
  {                                                                           \
    if ((T) < NTOK / 32 - 1) STAGE((CUR) ^ 1)                                 \
    short8 kf0 = *(const short8*)(ka0 + (CUR) * 2048);                        \
    short8 kf1 = *(const short8*)(ka1 + (CUR) * 2048);                        \
    short8 kf2 = *(const short8*)(ka2 + (CUR) * 2048);                        \
    short8 kf3 = *(const short8*)(ka3 + (CUR) * 2048);                        \
    f32x4 bv0 = *(const f32x4*)(ba0 + (CUR) * 4096);                          \
    f32x4 bv1 = *(const f32x4*)(ba1 + (CUR) * 4096);                          \
    f32x4 bv2 = *(const f32x4*)(ba2 + (CUR) * 4096);                          \
    f32x4 bv3 = *(const f32x4*)(ba3 + (CUR) * 4096);                          \
    short8 vA = *(const short8*)(va00 + (CUR) * 2048);                        \
    short8 vB = *(const short8*)(va01 + (CUR) * 2048);                        \
    short8 vC = *(const short8*)(va10 + (CUR) * 2048);                        \
    short8 vD = *(const short8*)(va11 + (CUR) * 2048);                        \
    f32x16 sacc = {};                                                         \
    __builtin_amdgcn_s_setprio(1);                                            \
    sacc = mfma32(kf0, qf[0], sacc);                                          \
    sacc = mfma32(kf1, qf[1], sacc);                                          \
    sacc = mfma32(kf2, qf[2], sacc);                                          \
    sacc = mfma32(kf3, qf[3], sacc);                                          \
    __builtin_amdgcn_s_setprio(0);                                            \
    float p[16];                                                              \
    _Pragma("unroll")                                                         \
    for (int r = 0; r < 4; ++r) {                                             \
      p[0 + r]  = exp2_hw(fmaf(bv0[r], LOG2E_, sacc[0 + r]));                 \
      p[4 + r]  = exp2_hw(fmaf(bv1[r], LOG2E_, sacc[4 + r]));                 \
      p[8 + r]  = exp2_hw(fmaf(bv2[r], LOG2E_, sacc[8 + r]));                 \
      p[12 + r] = exp2_hw(fmaf(bv3[r], LOG2E_, sacc[12 + r]));                \
    }                                                                         \
    unsigned Wd[4][2];                                                        \
    _Pragma("unroll")                                                         \
    for (int g = 0; g < 4; ++g) {                                             \
      Wd[g][0] = cvt_pk_bf16(p[g * 4], p[g * 4 + 1]);                         \
      Wd[g][1] = cvt_pk_bf16(p[g * 4 + 2], p[g * 4 + 3]);                     \
    }                                                                         \
    _Pragma("unroll")                                                         \
    for (int cc = 0; cc < 2; ++cc) {                                          \
      auto r0 = __builtin_amdgcn_permlane32_swap(Wd[cc * 2][0], Wd[cc * 2 + 1][0], false, false); \
      auto r1 = __builtin_amdgcn_permlane32_swap(Wd[cc * 2][1], Wd[cc * 2 + 1][1], false, false); \
      union { unsigned u[4]; short8 s; } pb;                                  \
      pb.u[0] = r0[0]; pb.u[1] = r1[0]; pb.u[2] = r0[1]; pb.u[3] = r1[1];     \
      __builtin_amdgcn_s_setprio(1);                                          \
      oacc0 = mfma32(cc ? vC : vA, pb.s, oacc0);                              \
      oacc1 = mfma32(cc ? vD : vB, pb.s, oacc1);                              \
      sumacc = mfma32(onesv, pb.s, sumacc);                                   \
      __builtin_amdgcn_s_setprio(0);                                          \
    }                                                                         \
    __syncthreads();                                                          \
  }

  STAGE(0)
  __syncthreads();

  for (int t = 0; t < NTOK / 32; t += 2) {
    BODY(t, 0)
    BODY(t + 1, 1)
  }
#undef BODY
#undef STAGE

  // epilogue: sumacc row 0 already holds the full row-sum for q = ql
  float inv = 1.f / sumacc[0];
  size_t obase = ((size_t)b * NTOK + qrow) * DIM + h * HDIM;
#pragma unroll
  for (int g = 0; g < 4; ++g) {
    unsigned u0 = cvt_pk_bf16(oacc0[g * 4] * inv, oacc0[g * 4 + 1] * inv);
    unsigned u1 = cvt_pk_bf16(oacc0[g * 4 + 2] * inv, oacc0[g * 4 + 3] * inv);
    uint2 pk0; pk0.x = u0; pk0.y = u1;
    *(uint2*)(Ob + obase + g * 8 + hi * 4) = pk0;
    unsigned u2 = cvt_pk_bf16(oacc1[g * 4] * inv, oacc1[g * 4 + 1] * inv);
    unsigned u3 = cvt_pk_bf16(oacc1[g * 4 + 2] * inv, oacc1[g * 4 + 3] * inv);
    uint2 pk1; pk1.x = u2; pk1.y = u3;
    *(uint2*)(Ob + obase + 32 + g * 8 + hi * 4) = pk1;
  }
}

// ---------------- output projection ----------------
__global__ __launch_bounds__(256, 2) void gemm_proj(const short* __restrict__ Ob,
    const short* __restrict__ wp, const float* __restrict__ bp, float* __restrict__ out) {
  __shared__ __align__(16) short As[128 * 64];
  __shared__ __align__(16) short Bs[128 * 64];
  int nt = blockIdx.x, mt = blockIdx.y;
  int tid = threadIdx.x, lane = tid & 63, w = tid >> 6;
  f32x4 acc[4][4] = {};
  gemm_mainloop(Ob, wp, mt * 128, nt * 128, As, Bs, acc, lane, w);
  int lr = lane & 15, lg = lane >> 4, wr = w >> 1, wc = w & 1;
#pragma unroll
  for (int j = 0; j < 4; ++j) {
    int n = nt * 128 + wc * 64 + j * 16 + lr;
    float bpv = bp[n];
#pragma unroll
    for (int i = 0; i < 4; ++i) {
      int m = mt * 128 + wr * 64 + i * 16 + lg * 4;
#pragma unroll
      for (int r = 0; r < 4; ++r)
        out[(size_t)(m + r) * DIM + n] = acc[i][j][r] + bpv;
    }
  }
}

extern "C" void kernel_launch(void* const* d_in, const int* in_sizes, int n_in,
                              void* d_out, int out_size, void* d_ws, size_t ws_size,
                              hipStream_t stream) {
  const float* x    = (const float*)d_in[0];
  const float* bias = (const float*)d_in[1];
  const float* Wq   = (const float*)d_in[2];
  const float* Wk   = (const float*)d_in[3];
  const float* Wv   = (const float*)d_in[4];
  const float* Wp   = (const float*)d_in[5];
  const float* bp   = (const float*)d_in[6];
  float* out = (float*)d_out;

  char* ws = (char*)d_ws;
  short* xb  = (short*)(ws);                    // 8192*768 bf16
  short* wqb = (short*)(ws + 12582912);
  short* wkb = (short*)(ws + 13762560);
  short* wvb = (short*)(ws + 14942208);
  short* wpb = (short*)(ws + 16121856);
  short* Qh  = (short*)(ws + 17301504);         // [b][h][n][64], pre-scaled by SC2
  short* Kh  = (short*)(ws + 29884416);
  short* Vt  = (short*)(ws + 42467328);         // [b][h][64][n]
  short* Ob  = (short*)(ws + 55050240);         // [b][n][768]

  cvt_x<<<6144, 256, 0, stream>>>(x, xb);
  cvt_w<<<dim3(576, 4), 256, 0, stream>>>(Wq, Wk, Wv, Wp, wqb, wkb, wvb, wpb);
  gemm_qkv<<<dim3(6, 64, 3), 256, 0, stream>>>(xb, wqb, wkb, wvb, Qh, Kh, Vt);
  attn_fused<<<768, 256, 0, stream>>>(Qh, Kh, Vt, bias, Ob);
  gemm_proj<<<dim3(6, 64), 256, 0, stream>>>(Ob, wpb, bp, out);
}